// Round 3
// baseline (81.803 us; speedup 1.0000x reference)
//
#include <hip/hip_runtime.h>

// Embedder: counts = scatter_add(one_hot(tokens)) -> (B, DEPTH) float32
// B=1024, S=200, DEPTH=100000. Output = 409.6 MB -> pure write-BW bound.
//
// Each block owns a 1/20-row segment (5000 floats = 20 KB LDS -> 8 blocks/CU,
// full 32-wave occupancy). Token loads are issued BEFORE the LDS zero so HBM
// latency hides under it. Counts built in LDS via ds_add_f32, then streamed
// to global exactly once with float4 stores (base = b*400000 + seg*20000,
// 16B-aligned). No global RMW; write phases of 8 resident blocks interleave.

#define EMB_DEPTH 100000
#define EMB_SEQ   200
#define NSEG      20
#define SEGSZ     (EMB_DEPTH / NSEG)   // 5000 floats = 20000 B

__global__ __launch_bounds__(256) void embedder_seg_kernel(
    const int*   __restrict__ tokens,     // (B, S) int32
    const float* __restrict__ on_values,  // (B, S) float32
    float*       __restrict__ out)        // (B, DEPTH) float32
{
    __shared__ float cnt[SEGSZ];

    const int tid = threadIdx.x;
    const int b   = blockIdx.x / NSEG;
    const int seg = blockIdx.x % NSEG;
    const int lo  = seg * SEGSZ;          // segment's first token id

    // Issue global loads early; latency hides under the LDS zero below.
    int   t = 0;
    float v = 0.0f;
    if (tid < EMB_SEQ) {
        t = tokens[(size_t)b * EMB_SEQ + tid];
        v = on_values[(size_t)b * EMB_SEQ + tid];
    }

    // Zero the LDS segment with ds_write_b128 (1250 stores / block).
    float4* c4z = reinterpret_cast<float4*>(cnt);
    const float4 z = make_float4(0.0f, 0.0f, 0.0f, 0.0f);
    #pragma unroll
    for (int i = tid; i < SEGSZ / 4; i += 256) c4z[i] = z;
    __syncthreads();

    // Scatter this row's tokens that land in our segment (ds_add_f32).
    if (tid < EMB_SEQ) {
        const unsigned r = (unsigned)(t - lo);
        if (r < (unsigned)SEGSZ) atomicAdd(&cnt[r], v);
    }
    __syncthreads();

    // Merged write-out: 1250 float4 per block, each line written exactly once.
    float4* out4 = reinterpret_cast<float4*>(out + (size_t)b * EMB_DEPTH + lo);
    const float4* c4 = reinterpret_cast<const float4*>(cnt);
    #pragma unroll
    for (int i = tid; i < SEGSZ / 4; i += 256) out4[i] = c4[i];
}

extern "C" void kernel_launch(void* const* d_in, const int* in_sizes, int n_in,
                              void* d_out, int out_size, void* d_ws, size_t ws_size,
                              hipStream_t stream) {
    const int*   tokens    = (const int*)  d_in[0];
    const float* on_values = (const float*)d_in[1];
    float*       out       = (float*)      d_out;

    const int B = in_sizes[0] / EMB_SEQ;   // 1024
    embedder_seg_kernel<<<B * NSEG, 256, 0, stream>>>(tokens, on_values, out);
}